// Round 1
// baseline (468.490 us; speedup 1.0000x reference)
//
#include <hip/hip_runtime.h>

#define NN 50000
#define EE 800000
#define DD 128
#define RR 8
#define CELLS (NN * RR)            // 400000 (rel, dst) cells, key = rel*NN + dst (REL-MAJOR)
#define TILE_N 64
#define NBLK ((NN + TILE_N - 1) / TILE_N)          // 782
#define SCAN_CHUNK 1024
#define SCAN_BLOCKS ((CELLS + SCAN_CHUNK - 1) / SCAN_CHUNK)   // 391

typedef __attribute__((ext_vector_type(4))) float f32x4;
typedef __attribute__((ext_vector_type(8))) short s16x8;
union ABu { uint4 q; s16x8 v; };

// ---------------- bf16 helpers ----------------

__device__ __forceinline__ unsigned int packbf2(float a, float b) {
    unsigned int ua = __float_as_uint(a);
    unsigned int ub = __float_as_uint(b);
    ua = (ua + 0x7fffu + ((ua >> 16) & 1u)) >> 16;           // RNE, low half
    ub = (ub + 0x7fffu + ((ub >> 16) & 1u)) & 0xffff0000u;   // RNE, high half
    return ua | ub;
}

// ---------------- fused prep: to_bf16 + wpack + rpack + count_cells ----------------
#define NB_A ((NN * 32 + 255) / 256)    // 6250: x -> packed bf16 (float4 -> uint2)
#define NB_B 128                        // wpack: 32768 items
#define NB_C 32                         // rpack: 8192 items
#define NB_D ((EE + 255) / 256)         // 3125: count_cells

__global__ void prep_fused(const float* __restrict__ x, unsigned int* __restrict__ xb,
                           const float* __restrict__ W1, const float* __restrict__ W2,
                           unsigned int* __restrict__ Wb1, unsigned int* __restrict__ Wb2,
                           const float* __restrict__ r1, const float* __restrict__ r2,
                           unsigned int* __restrict__ rb1, unsigned int* __restrict__ rb2,
                           const int* __restrict__ dst, const int* __restrict__ et,
                           int* __restrict__ cnt) {
    int bid = blockIdx.x, tid = threadIdx.x;
    if (bid < NB_A) {
        int i = bid * 256 + tid;
        if (i < NN * 32) {
            float4 v = ((const float4*)x)[i];
            ((uint2*)xb)[i] = make_uint2(packbf2(v.x, v.y), packbf2(v.z, v.w));
        }
    } else if (bid < NB_A + NB_B) {
        // W [16 blocks of 64x64, row-major (k,n)] -> Wb [block][n][kp]
        int i = (bid - NB_A) * 256 + tid;
        int kp = i & 31, n = (i >> 5) & 63, rb = i >> 11;
        int s0 = (rb * 64 + 2 * kp) * 64 + n;
        int s1 = (rb * 64 + 2 * kp + 1) * 64 + n;
        Wb1[((rb * 64 + n) * 32) + kp] = packbf2(W1[s0], W1[s1]);
        Wb2[((rb * 64 + n) * 32) + kp] = packbf2(W2[s0], W2[s1]);
    } else if (bid < NB_A + NB_B + NB_C) {
        // root [128k x 128n] -> rb [n][kp]
        int i = (bid - NB_A - NB_B) * 256 + tid;
        int kp = i & 63, n = i >> 6;
        int s0 = (2 * kp) * 128 + n, s1 = (2 * kp + 1) * 128 + n;
        rb1[n * 64 + kp] = packbf2(r1[s0], r1[s1]);
        rb2[n * 64 + kp] = packbf2(r2[s0], r2[s1]);
    } else {
        int e = (bid - NB_A - NB_B - NB_C) * 256 + tid;
        if (e < EE) atomicAdd(&cnt[et[e] * NN + dst[e]], 1);
    }
}

// ---------------- prep: scans + scatter (CSR by cell = rel*NN + dst) ----------------

__global__ __launch_bounds__(256) void scan1(const int* __restrict__ cnt,
                                             int* __restrict__ off, int* __restrict__ bsum) {
    __shared__ int s[256];
    int tid = threadIdx.x;
    int base = blockIdx.x * SCAN_CHUNK + tid * 4;
    int v[4];
#pragma unroll
    for (int i = 0; i < 4; ++i) v[i] = (base + i < CELLS) ? cnt[base + i] : 0;
    int tot = v[0] + v[1] + v[2] + v[3];
    s[tid] = tot;
    __syncthreads();
    for (int d = 1; d < 256; d <<= 1) {
        int t = (tid >= d) ? s[tid - d] : 0;
        __syncthreads();
        s[tid] += t;
        __syncthreads();
    }
    int excl = s[tid] - tot;
    if (tid == 255) bsum[blockIdx.x] = s[255];
    int run = excl;
#pragma unroll
    for (int i = 0; i < 4; ++i) {
        if (base + i < CELLS) off[base + i] = run;
        run += v[i];
    }
}

// merged scan2+scan3: each block reduces its own chunk-prefix from bsum, then finalizes
__global__ __launch_bounds__(256) void scan3(int* __restrict__ off, const int* __restrict__ bsum,
                                             int* __restrict__ cur) {
    __shared__ int red[256];
    int tid = threadIdx.x, bid = blockIdx.x;
    int a = 0;
    for (int i = tid; i < bid; i += 256) a += bsum[i];
    red[tid] = a;
    __syncthreads();
#pragma unroll
    for (int d = 128; d > 0; d >>= 1) {
        if (tid < d) red[tid] += red[tid + d];
        __syncthreads();
    }
    int add = red[0];
    int base = bid * SCAN_CHUNK + tid * 4;
#pragma unroll
    for (int i = 0; i < 4; ++i) {
        int c = base + i;
        if (c < CELLS) {
            int o = off[c] + add;
            off[c] = o;
            cur[c] = o;
        }
    }
    if (bid == 0 && tid == 0) off[CELLS] = EE;   // sentinel
}

__global__ void cell_scatter(const int* __restrict__ src, const int* __restrict__ dst,
                             const int* __restrict__ et, int* __restrict__ cur,
                             int* __restrict__ esrc) {
    int e = blockIdx.x * blockDim.x + threadIdx.x;
    if (e < EE) {
        int cell = et[e] * NN + dst[e];
        int pos = atomicAdd(&cur[cell], 1);
        esrc[pos] = src[e];
    }
}

// ---------------- fused layer, MFMA GEMM ----------------
// Gather v2: wave-serial, edge-balanced, fully coalesced.
//   cell = r*NN + node; wave w owns 16 consecutive cells -> ONE contiguous esrc range.
//   lane = feature-pair: each edge's 256B bf16 row is one coalesced global_load_dword
//   (scalar base + lane*4B).  Per-cell fp32 mean in 2 VGPRs; boundary walk via __shfl.
//   8-deep chunked prefetch of esrc + rows hides L2/L3 latency.
// LDS: double-buffered MTb 2x[64 kp][66] uint (33.8KB) union OUT 64x130 f32 -> 4 blk/CU.
// One barrier per relation (gather(r+1) writes the other buffer than mfma(r) reads).
template <int RELU, int WRITEF, int WRITEB>
__global__ __launch_bounds__(256, 4) void layer_fused(
    const unsigned int* __restrict__ xgb, const int* __restrict__ esrc,
    const int* __restrict__ off,
    const unsigned int* __restrict__ Wb, const unsigned int* __restrict__ rootb,
    const float* __restrict__ bias, float* __restrict__ outf,
    unsigned int* __restrict__ outb) {

    __shared__ unsigned int SH[8448];       // 33792 B

    int tid = threadIdx.x;
    int n0 = blockIdx.x * TILE_N;
    int w = tid >> 6, l = tid & 63;
    int quad = l >> 4, li = l & 15;
    int b = w >> 1;                          // out-half this wave serves
    int n0w = n0 + 16 * w;                   // first node of this wave's cell group
    int mtw = l * 66 + 16 * w;               // LDS write base: row = feature-pair l

    f32x4 acc[4][2];
#pragma unroll
    for (int s = 0; s < 2; ++s) {
        float bb = bias[32 * w + 16 * s + li];
#pragma unroll
        for (int mt = 0; mt < 4; ++mt) {
            acc[mt][s][0] = bb; acc[mt][s][1] = bb; acc[mt][s][2] = bb; acc[mt][s][3] = bb;
        }
    }

    // boundaries for r=0: lane i (i<=16) holds off[clamp(n0w+i)]
    int bvals = 0;
    if (l <= 16) {
        int nd = n0w + l; if (nd > NN) nd = NN;      // tail cells clamp to empty range
        bvals = off[nd];
    }

    for (int r = 0; r < RR; ++r) {
        unsigned int* MT = SH + (r & 1) * 4224;

        // ---- balanced gather-mean: wave-serial over its contiguous edge range ----
        int obeg = __shfl(bvals, 0);
        int oend = __shfl(bvals, 16);
        int cl = 0, sbeg = obeg;
        int nb = __shfl(bvals, 1);
        float a0 = 0.f, a1 = 0.f;

        for (int t0 = obeg; t0 < oend; t0 += 8) {
            int m = oend - t0; if (m > 8) m = 8;
            int sv[8]; unsigned int rv[8];
#pragma unroll
            for (int i = 0; i < 8; ++i) if (i < m) sv[i] = esrc[t0 + i];       // broadcast
#pragma unroll
            for (int i = 0; i < 8; ++i) if (i < m) rv[i] = xgb[(sv[i] << 6) + l]; // 256B/wave
#pragma unroll
            for (int i = 0; i < 8; ++i) if (i < m) {
                int t = t0 + i;
                while (t >= nb) {                    // finish cells up to edge t's cell
                    float sc = 1.0f / (float)max(nb - sbeg, 1);
                    MT[mtw + cl] = packbf2(a0 * sc, a1 * sc);
                    a0 = 0.f; a1 = 0.f; sbeg = nb; ++cl;
                    nb = __shfl(bvals, min(cl + 1, 16));
                }
                a0 += __uint_as_float(rv[i] << 16);
                a1 += __uint_as_float(rv[i] & 0xffff0000u);
            }
        }
        while (cl < 16) {                            // drain trailing (possibly empty) cells
            float sc = 1.0f / (float)max(nb - sbeg, 1);
            MT[mtw + cl] = packbf2(a0 * sc, a1 * sc);
            a0 = 0.f; a1 = 0.f; sbeg = nb; ++cl;
            nb = __shfl(bvals, min(cl + 1, 16));
        }

        // prefetch next relation's boundaries; latency hides under barrier+mfma
        int bvn = 0;
        if (l <= 16 && r + 1 < RR) {
            int nd = n0w + l; if (nd > NN) nd = NN;
            bvn = off[(r + 1) * NN + nd];
        }
        __syncthreads();

        // ---- block-diag GEMM: 16 mfma/wave; A from MT, B from global Wb (L1-hot) ----
        const uint4* WbB = (const uint4*)(Wb + (((size_t)r * 2 + b) * 64) * 32);
        int nl0 = (w & 1) * 32 + li;
#pragma unroll
        for (int kc = 0; kc < 2; ++kc) {
            ABu bf0, bf1;
            bf0.q = WbB[nl0 * 8 + 4 * kc + quad];
            bf1.q = WbB[(nl0 + 16) * 8 + 4 * kc + quad];
#pragma unroll
            for (int mt = 0; mt < 4; ++mt) {
                ABu af;
                int base = (32 * b + 16 * kc + 4 * quad) * 66 + 16 * mt + li;
                af.q.x = MT[base]; af.q.y = MT[base + 66];
                af.q.z = MT[base + 132]; af.q.w = MT[base + 198];
                acc[mt][0] = __builtin_amdgcn_mfma_f32_16x16x32_bf16(af.v, bf0.v, acc[mt][0], 0, 0, 0);
                acc[mt][1] = __builtin_amdgcn_mfma_f32_16x16x32_bf16(af.v, bf1.v, acc[mt][1], 0, 0, 0);
            }
        }
        bvals = bvn;
        // no second barrier: gather(r+1) writes the OTHER buffer; barrier(r) already
        // guarantees every wave is past mfma(r-1) (last reader of that buffer).
    }

    // ---- root term: buf0 <- own row (disjoint from buf1 read by any wave in r=7 mfma) ----
    {
        int node = n0 + l;
        if (node < NN) {
            const uint4* xr = (const uint4*)(xgb + (size_t)node * 64 + w * 16);
            uint4 X[4] = {xr[0], xr[1], xr[2], xr[3]};
#pragma unroll
            for (int i = 0; i < 4; ++i) {
                SH[(16 * w + 4 * i + 0) * 66 + l] = X[i].x;
                SH[(16 * w + 4 * i + 1) * 66 + l] = X[i].y;
                SH[(16 * w + 4 * i + 2) * 66 + l] = X[i].z;
                SH[(16 * w + 4 * i + 3) * 66 + l] = X[i].w;
            }
        } else {
#pragma unroll
            for (int i = 0; i < 16; ++i) SH[(16 * w + i) * 66 + l] = 0u;
        }
    }
    __syncthreads();

    // root GEMM: K=128 -> 4 k-chunks, 32 mfma/wave
    const uint4* RbB = (const uint4*)rootb;
#pragma unroll
    for (int kc = 0; kc < 4; ++kc) {
        ABu bf0, bf1;
        bf0.q = RbB[(32 * w + li) * 16 + 4 * kc + quad];
        bf1.q = RbB[(32 * w + 16 + li) * 16 + 4 * kc + quad];
#pragma unroll
        for (int mt = 0; mt < 4; ++mt) {
            ABu af;
            int base = (16 * kc + 4 * quad) * 66 + 16 * mt + li;
            af.q.x = SH[base]; af.q.y = SH[base + 66];
            af.q.z = SH[base + 132]; af.q.w = SH[base + 198];
            acc[mt][0] = __builtin_amdgcn_mfma_f32_16x16x32_bf16(af.v, bf0.v, acc[mt][0], 0, 0, 0);
            acc[mt][1] = __builtin_amdgcn_mfma_f32_16x16x32_bf16(af.v, bf1.v, acc[mt][1], 0, 0, 0);
        }
    }
    __syncthreads();

    // ---- epilogue: stage D to LDS (fp32, stride 130), then coalesced stores ----
    float* OF = (float*)SH;
#pragma unroll
    for (int mt = 0; mt < 4; ++mt)
#pragma unroll
        for (int s = 0; s < 2; ++s)
#pragma unroll
            for (int reg = 0; reg < 4; ++reg)
                OF[(16 * mt + 4 * quad + reg) * 130 + 32 * w + 16 * s + li] = acc[mt][s][reg];
    __syncthreads();

    if (WRITEB) {
        int p = tid & 63, rg = tid >> 6;     // pair-col, row-group (4 rows/pass)
#pragma unroll 4
        for (int it = 0; it < 16; ++it) {
            int ee = it * 4 + rg, row = n0 + ee;
            if (row < NN) {
                float v0 = OF[ee * 130 + 2 * p], v1 = OF[ee * 130 + 2 * p + 1];
                if (RELU) { v0 = fmaxf(v0, 0.f); v1 = fmaxf(v1, 0.f); }
                outb[(size_t)row * 64 + p] = packbf2(v0, v1);
            }
        }
    }
    if (WRITEF) {
        int d4 = (tid & 31) * 4, rg = tid >> 5;   // 8 rows/pass
#pragma unroll 4
        for (int it = 0; it < 8; ++it) {
            int ee = it * 8 + rg, row = n0 + ee;
            if (row < NN) {
                float4 v = make_float4(OF[ee * 130 + d4], OF[ee * 130 + d4 + 1],
                                       OF[ee * 130 + d4 + 2], OF[ee * 130 + d4 + 3]);
                if (RELU) {
                    v.x = fmaxf(v.x, 0.f); v.y = fmaxf(v.y, 0.f);
                    v.z = fmaxf(v.z, 0.f); v.w = fmaxf(v.w, 0.f);
                }
                *(float4*)(outf + (size_t)row * DD + d4) = v;
            }
        }
    }
}

// ---------------- driver ----------------

extern "C" void kernel_launch(void* const* d_in, const int* in_sizes, int n_in,
                              void* d_out, int out_size, void* d_ws, size_t ws_size,
                              hipStream_t stream) {
    const float* x     = (const float*)d_in[0];
    const int*   ei    = (const int*)d_in[1];
    const int*   src   = ei;
    const int*   dstp  = ei + EE;
    const int*   et    = (const int*)d_in[2];
    const float* W1    = (const float*)d_in[3];
    const float* root1 = (const float*)d_in[4];
    const float* b1    = (const float*)d_in[5];
    const float* W2    = (const float*)d_in[6];
    const float* root2 = (const float*)d_in[7];
    const float* b2    = (const float*)d_in[8];
    float* out = (float*)d_out;

    // ws layout (4 B elements)
    unsigned int* xb  = (unsigned int*)d_ws;         // NN*64 packed bf16 pairs
    unsigned int* hb  = xb + (size_t)NN * 64;        // NN*64
    int* cnt  = (int*)(hb + (size_t)NN * 64);        // CELLS
    int* off  = cnt + CELLS;                         // CELLS + 1
    int* cur  = off + CELLS + 1;                     // CELLS
    int* bsum = cur + CELLS;                         // 512
    int* esrc = bsum + 512;                          // EE
    unsigned int* Wb1 = (unsigned int*)(esrc + EE);  // 32768
    unsigned int* Wb2 = Wb1 + 32768;                 // 32768
    unsigned int* rb1 = Wb2 + 32768;                 // 8192
    unsigned int* rb2 = rb1 + 8192;                  // 8192

    hipMemsetAsync(cnt, 0, CELLS * sizeof(int), stream);
    prep_fused<<<NB_A + NB_B + NB_C + NB_D, 256, 0, stream>>>(
        x, xb, W1, W2, Wb1, Wb2, root1, root2, rb1, rb2, dstp, et, cnt);
    scan1<<<SCAN_BLOCKS, 256, 0, stream>>>(cnt, off, bsum);
    scan3<<<SCAN_BLOCKS, 256, 0, stream>>>(off, bsum, cur);
    cell_scatter<<<(EE + 255) / 256, 256, 0, stream>>>(src, dstp, et, cur, esrc);

    // layer 1: bf16 h out;  layer 2: fp32 out
    layer_fused<1, 0, 1><<<NBLK, 256, 0, stream>>>(xb, esrc, off, Wb1, rb1, b1,
                                                   nullptr, hb);
    layer_fused<0, 1, 0><<<NBLK, 256, 0, stream>>>(hb, esrc, off, Wb2, rb2, b2,
                                                   out, nullptr);
}